// Round 5
// baseline (19.085 us; speedup 1.0000x reference)
//
#include <hip/hip_runtime.h>

// SvmLoss N=8192, RANK_RATIO=1.0 -> out = rank_loss (scalar f32).
// rank_loss = sum_{i,j} [t_i<t_j && status_i==1] * max(1+logit_j-logit_i,0)^2
//             / max(#pairs,1)
//
// R5: packed-fp32 inner loop. hinge = max((1+lj) - li, 0) = -min(li-(1+lj), 0),
// so hinge^2 = min(x,0)^2 with x = li + (-(1+lj)). The sub (v_pk_add_f32) and
// accumulate (v_pk_fma_f32) are packed: 16 VALU per 4 pairs (was 20).
// status folded into t_eff = status==1 ? t : 1e30 at staging time.
// GRID=2048 -> 8 blocks/CU = 8 waves/SIMD for latency hiding.
// Two-kernel deterministic reduce (R4: atomic tail costs ~20us, avoid).

typedef float f32x2 __attribute__((ext_vector_type(2)));

constexpr int N_   = 8192;
constexpr int BLK  = 256;
constexpr int R    = 4;               // j columns per lane
constexpr int JPB  = BLK * R;         // 1024 j per block
constexpr int NJB  = N_ / JPB;        // 8 j-blocks
constexpr int ICH  = 32;              // i per chunk
constexpr int NIC  = N_ / ICH;        // 256 i-chunks
constexpr int GRID = NJB * NIC;       // 2048 blocks = 8/CU, 8 waves/SIMD

__global__ __launch_bounds__(BLK) void svm_partial(
        const float* __restrict__ logit,
        const float* __restrict__ st,      // [N][2] status,time
        float* __restrict__ psum,
        int*   __restrict__ pcnt) {
    __shared__ float2 ci_s[ICH];          // (logit_i, t_eff_i)

    const int jb = blockIdx.x & (NJB - 1);
    const int ic = blockIdx.x / NJB;
    const int j0 = jb * JPB + (int)threadIdx.x * R;   // 16B-aligned

    const float4 lj4 = *(const float4*)(logit + j0);
    const float4 sa  = *(const float4*)(st + 2 * j0);      // (s,t) j0,j0+1
    const float4 sb  = *(const float4*)(st + 2 * j0 + 4);  // (s,t) j0+2,j0+3
    // nljp = -(1 + logit_j); x = li + nljp = li - (1+lj)
    const f32x2 nljpA = { -(1.0f + lj4.x), -(1.0f + lj4.y) };
    const f32x2 nljpB = { -(1.0f + lj4.z), -(1.0f + lj4.w) };
    const float tj0 = sa.y, tj1 = sa.w, tj2 = sb.y, tj3 = sb.w;

    const int i0 = ic * ICH;
    if (threadIdx.x < ICH) {
        const int    i  = i0 + (int)threadIdx.x;
        const float  li = logit[i];
        const float2 sv = *(const float2*)(st + 2 * i);
        const float  te = (sv.x == 1.0f) ? sv.y : 1e30f;   // status gate
        ci_s[threadIdx.x] = make_float2(li, te);
    }
    __syncthreads();

    f32x2 sA = {0.f, 0.f}, sB = {0.f, 0.f};
    int cnt = 0;                          // wave-uniform -> SGPR
    #pragma unroll 8
    for (int k = 0; k < ICH; ++k) {
        const float2 ct = ci_s[k];        // ds_read_b64 broadcast
        const float  li = ct.x, te = ct.y;
        const f32x2  li2 = { li, li };
        f32x2 xA = li2 + nljpA;           // v_pk_add_f32
        f32x2 xB = li2 + nljpB;
        float h0 = fminf(xA.x, 0.f);      // -hinge
        float h1 = fminf(xA.y, 0.f);
        float h2 = fminf(xB.x, 0.f);
        float h3 = fminf(xB.y, 0.f);
        const bool m0 = te < tj0;
        const bool m1 = te < tj1;
        const bool m2 = te < tj2;
        const bool m3 = te < tj3;
        f32x2 hmA = { m0 ? h0 : 0.f, m1 ? h1 : 0.f };
        f32x2 hmB = { m2 ? h2 : 0.f, m3 ? h3 : 0.f };
        sA += hmA * hmA;                  // v_pk_fma_f32
        sB += hmB * hmB;
        cnt += (int)__popcll(__ballot(m0));
        cnt += (int)__popcll(__ballot(m1));
        cnt += (int)__popcll(__ballot(m2));
        cnt += (int)__popcll(__ballot(m3));
    }

    float sum = (sA.x + sA.y) + (sB.x + sB.y);
    for (int off = 32; off > 0; off >>= 1)
        sum += __shfl_down(sum, off, 64);

    __shared__ float wsum[BLK / 64];
    __shared__ int   wcnt[BLK / 64];
    const int lane = threadIdx.x & 63;
    const int wid  = threadIdx.x >> 6;
    if (lane == 0) { wsum[wid] = sum; wcnt[wid] = cnt; }
    __syncthreads();
    if (threadIdx.x == 0) {
        psum[blockIdx.x] = (wsum[0] + wsum[1]) + (wsum[2] + wsum[3]);
        pcnt[blockIdx.x] =  wcnt[0] + wcnt[1] + wcnt[2] + wcnt[3];
    }
}

__global__ __launch_bounds__(BLK) void svm_final(
        const float* __restrict__ psum,
        const int* __restrict__ pcnt,
        float* __restrict__ out) {
    float s = 0.f;
    int   c = 0;
    for (int t = (int)threadIdx.x; t < GRID; t += BLK) {   // fixed order
        s += psum[t];
        c += pcnt[t];
    }
    for (int off = 32; off > 0; off >>= 1) {
        s += __shfl_down(s, off, 64);
        c += __shfl_down(c, off, 64);
    }
    __shared__ float wsum[BLK / 64];
    __shared__ int   wcnt[BLK / 64];
    const int lane = threadIdx.x & 63;
    const int wid  = threadIdx.x >> 6;
    if (lane == 0) { wsum[wid] = s; wcnt[wid] = c; }
    __syncthreads();
    if (threadIdx.x == 0) {
        const float S = (wsum[0] + wsum[1]) + (wsum[2] + wsum[3]);
        const int   C =  wcnt[0] + wcnt[1] + wcnt[2] + wcnt[3];
        out[0] = S / (float)(C > 0 ? C : 1);
    }
}

extern "C" void kernel_launch(void* const* d_in, const int* in_sizes, int n_in,
                              void* d_out, int out_size, void* d_ws, size_t ws_size,
                              hipStream_t stream) {
    const float* logit = (const float*)d_in[0];   // (N,1) f32
    const float* st    = (const float*)d_in[1];   // (N,2) f32

    float* psum = (float*)d_ws;                      // [GRID]
    int*   pcnt = (int*)((char*)d_ws + GRID * 4);    // [GRID]

    svm_partial<<<GRID, BLK, 0, stream>>>(logit, st, psum, pcnt);
    svm_final<<<1, BLK, 0, stream>>>(psum, pcnt, (float*)d_out);
}